// Round 9
// baseline (229.917 us; speedup 1.0000x reference)
//
#include <hip/hip_runtime.h>

// ---------------------------------------------------------------------------
// LSH attention, MI355X.  B=2, S=2048, E=1024, H=16, Dh=64, NB=64, NH=6.
// ALL inputs/outputs are FP32.
// R8 (resubmit; infra failed): (a) gemm reverted to R5 (BK=64, bounds(256,2)):
// R7's BK=32 doubled barrier count and regressed ~12us.  (b) attn SPLIT-K:
// grid (32,16,2), each z-half sweeps HALF the K range -> per-block staging
// halves, total staged bytes UNCHANGED (fixes R2's confound), blocks
// 512->1024 = 4/CU = 16 waves/CU.  Fixed upper-bound softmax makes partials
// exactly mergeable: out = (o0+o1)/(l0+l1) via a 4096-block merge kernel.
// Partials live in dead workspace (xh/xl region + old Qf region + Wqh).
//   0) split_all: x -> xh+xl, Wq -> Wqh+Wql, Wv -> Wvh in ONE launch
//   1) gemm_qv: 512 blocks, 128x128, BK=64 (R5 exact)
//   2) bucket_kernel: bucket bits from hi+lo q; row |q|^2
//   3) attn_kernel: (32,16,2), 4 waves x 32 q-rows, K-tile 64, half-sweep
//   4) merge_kernel: out = (o0+o1)/(l0+l1)
// ---------------------------------------------------------------------------

typedef short short8 __attribute__((ext_vector_type(8)));
typedef float f32x4 __attribute__((ext_vector_type(4)));
typedef unsigned short us4 __attribute__((ext_vector_type(4)));

__device__ __forceinline__ float bff(unsigned short h) {
    return __uint_as_float(((unsigned int)h) << 16);
}
__device__ __forceinline__ unsigned short f2bf(float f) {  // RNE, finite inputs
    unsigned int u = __float_as_uint(f);
    u += 0x7fffu + ((u >> 16) & 1u);
    return (unsigned short)(u >> 16);
}

__device__ __forceinline__ void glds16(const unsigned short* g, unsigned short* l) {
    __builtin_amdgcn_global_load_lds(
        (const __attribute__((address_space(1))) unsigned int*)g,
        (__attribute__((address_space(3))) unsigned int*)l, 16, 0, 0);
}

// ---------------------------------------------------------------------------
// Fused split: blk<4096 -> x (hi+lo); <5120 -> Wq (hi+lo); else Wv (hi).
// ---------------------------------------------------------------------------
__global__ __launch_bounds__(256) void split_all(
    const float* __restrict__ x, const float* __restrict__ Wq,
    const float* __restrict__ Wv,
    unsigned short* __restrict__ xh, unsigned short* __restrict__ xl,
    unsigned short* __restrict__ Wqh, unsigned short* __restrict__ Wql,
    unsigned short* __restrict__ Wvh)
{
    const int blk = blockIdx.x;
    const float* in;
    unsigned short *hi, *lo;
    int idx;
    if (blk < 4096) {
        idx = blk * 256 + threadIdx.x; in = x; hi = xh; lo = xl;
    } else if (blk < 5120) {
        idx = (blk - 4096) * 256 + threadIdx.x; in = Wq; hi = Wqh; lo = Wql;
    } else {
        idx = (blk - 5120) * 256 + threadIdx.x; in = Wv; hi = Wvh; lo = nullptr;
    }
    const float4 v = ((const float4*)in)[idx];
    us4 h;
    h.x = f2bf(v.x); h.y = f2bf(v.y); h.z = f2bf(v.z); h.w = f2bf(v.w);
    ((us4*)hi)[idx] = h;
    if (lo) {
        us4 l;
        l.x = f2bf(v.x - bff(h.x)); l.y = f2bf(v.y - bff(h.y));
        l.z = f2bf(v.z - bff(h.z)); l.w = f2bf(v.w - bff(h.w));
        ((us4*)lo)[idx] = l;
    }
}

// ---------------------------------------------------------------------------
// Merged projection GEMM (R5 exact).  512 blocks: b<256 Q path (3-term
// hi/lo); b>=256 V path.  128x128 tile, BK=64, LDS staged with global-side
// XOR swizzle.  launch_bounds (256,2) -> <=128 VGPR -> 2 blocks/CU.
// ---------------------------------------------------------------------------
__global__ __launch_bounds__(256, 2) void gemm_qv(
    const unsigned short* __restrict__ xh, const unsigned short* __restrict__ xl,
    const unsigned short* __restrict__ wqh, const unsigned short* __restrict__ wql,
    const unsigned short* __restrict__ wvh,
    const float* __restrict__ bq, const float* __restrict__ bv,
    unsigned short* __restrict__ Qb, unsigned short* __restrict__ Qlo,
    unsigned short* __restrict__ Vt)
{
    __shared__ unsigned short Ah[128 * 64], Al[128 * 64];
    __shared__ unsigned short Bh[128 * 64], Bl[128 * 64];

    const int tid = threadIdx.x;
    const int w = tid >> 6, lane = tid & 63;
    const int i = lane & 15, qd = lane >> 4;
    const int l8 = lane >> 3, j = lane & 7;
    const int nw = w * 32;
    const int blk = blockIdx.x;
    const bool isq = blk < 256;

    f32x4 acc[8][2];
#pragma unroll
    for (int a = 0; a < 8; ++a)
#pragma unroll
        for (int b2 = 0; b2 < 2; ++b2) acc[a][b2] = f32x4{0.f, 0.f, 0.f, 0.f};

    const int gro = ((j ^ l8) << 3);

    if (isq) {
        const int m0 = (blk >> 3) * 128;   // token tile
        const int n0 = (blk & 7) * 128;    // channel tile
        for (int k0 = 0; k0 < 1024; k0 += 64) {
            __syncthreads();
#pragma unroll
            for (int c = 0; c < 4; ++c) {
                const int r = w * 32 + c * 8;
                const size_t gx = (size_t)(m0 + r + l8) * 1024 + k0 + gro;
                const size_t gw = (size_t)(n0 + r + l8) * 1024 + k0 + gro;
                glds16(xh + gx, &Ah[r * 64]);
                glds16(xl + gx, &Al[r * 64]);
                glds16(wqh + gw, &Bh[r * 64]);
                glds16(wql + gw, &Bl[r * 64]);
            }
            __syncthreads();
#pragma unroll
            for (int kc = 0; kc < 2; ++kc) {
                const int ch = (((kc * 4 + qd) ^ (i & 7)) << 3);
                short8 bh2[2], bl2[2];
#pragma unroll
                for (int nn = 0; nn < 2; ++nn) {
                    bh2[nn] = *(const short8*)&Bh[(nw + nn * 16 + i) * 64 + ch];
                    bl2[nn] = *(const short8*)&Bl[(nw + nn * 16 + i) * 64 + ch];
                }
#pragma unroll
                for (int mm = 0; mm < 8; ++mm) {
                    const short8 ah = *(const short8*)&Ah[(mm * 16 + i) * 64 + ch];
                    const short8 al = *(const short8*)&Al[(mm * 16 + i) * 64 + ch];
#pragma unroll
                    for (int nn = 0; nn < 2; ++nn) {
                        acc[mm][nn] = __builtin_amdgcn_mfma_f32_16x16x32_bf16(
                            ah, bh2[nn], acc[mm][nn], 0, 0, 0);
                        acc[mm][nn] = __builtin_amdgcn_mfma_f32_16x16x32_bf16(
                            al, bh2[nn], acc[mm][nn], 0, 0, 0);
                        acc[mm][nn] = __builtin_amdgcn_mfma_f32_16x16x32_bf16(
                            ah, bl2[nn], acc[mm][nn], 0, 0, 0);
                    }
                }
            }
        }
#pragma unroll
        for (int mm = 0; mm < 8; ++mm)
#pragma unroll
            for (int nn = 0; nn < 2; ++nn)
#pragma unroll
                for (int rr = 0; rr < 4; ++rr) {
                    const int row = m0 + mm * 16 + qd * 4 + rr;  // token
                    const int col = n0 + nw + nn * 16 + i;       // channel
                    const float v = acc[mm][nn][rr] + bq[col];
                    const unsigned short hs = f2bf(v);
                    const float lo = v - bff(hs);
                    const int b = row >> 11, s = row & 2047;
                    const int hh = col >> 6, d = col & 63;
                    const size_t oi = ((size_t)((b << 4) + hh) * 2048 + s) * 64 + d;
                    Qb[oi] = hs;
                    Qlo[oi] = f2bf(lo);
                }
    } else {
        const int b2 = blk - 256;
        const int m0 = (b2 & 7) * 128;     // channel tile
        const int n0 = (b2 >> 3) * 128;    // token tile
        for (int k0 = 0; k0 < 1024; k0 += 64) {
            __syncthreads();
#pragma unroll
            for (int c = 0; c < 4; ++c) {
                const int r = w * 32 + c * 8;
                glds16(wvh + (size_t)(m0 + r + l8) * 1024 + k0 + gro, &Ah[r * 64]);
                glds16(xh + (size_t)(n0 + r + l8) * 1024 + k0 + gro, &Bh[r * 64]);
            }
            __syncthreads();
#pragma unroll
            for (int kc = 0; kc < 2; ++kc) {
                const int ch = (((kc * 4 + qd) ^ (i & 7)) << 3);
                short8 bf2[2];
#pragma unroll
                for (int nn = 0; nn < 2; ++nn)
                    bf2[nn] = *(const short8*)&Bh[(nw + nn * 16 + i) * 64 + ch];
#pragma unroll
                for (int mm = 0; mm < 8; ++mm) {
                    const short8 af = *(const short8*)&Ah[(mm * 16 + i) * 64 + ch];
#pragma unroll
                    for (int nn = 0; nn < 2; ++nn)
                        acc[mm][nn] = __builtin_amdgcn_mfma_f32_16x16x32_bf16(
                            af, bf2[nn], acc[mm][nn], 0, 0, 0);
                }
            }
        }
#pragma unroll
        for (int mm = 0; mm < 8; ++mm)
#pragma unroll
            for (int nn = 0; nn < 2; ++nn)
#pragma unroll
                for (int rr = 0; rr < 4; ++rr) {
                    const int rch = m0 + mm * 16 + qd * 4 + rr;  // channel
                    const int tok = n0 + nw + nn * 16 + i;       // token
                    const float v = acc[mm][nn][rr] + bv[rch];
                    const int b = tok >> 11, s = tok & 2047;
                    Vt[((size_t)(b * 1024 + rch)) * 2048 + s] = f2bf(v);
                }
    }
}

// ---------------------------------------------------------------------------
// Buckets + row norms.  q reconstructed as hi+lo from Qb/Qlo.
// ---------------------------------------------------------------------------
__global__ __launch_bounds__(256) void bucket_kernel(
    const unsigned short* __restrict__ Qb, const unsigned short* __restrict__ Qlo,
    const float* __restrict__ hp,
    int* __restrict__ buckets, float* __restrict__ rown)
{
    __shared__ float hpl[65 * 6];
    const int tid = threadIdx.x;
    if (tid < 65 * 6) hpl[tid] = hp[tid];
    __syncthreads();

    const int idx = blockIdx.x * 256 + tid;       // 65536 = 32 bh * 2048 s
    const unsigned short* qh = Qb + (size_t)idx * 64;
    const unsigned short* ql = Qlo + (size_t)idx * 64;

    float pj[6];
    float nrm = 0.f;
#pragma unroll
    for (int n = 0; n < 6; ++n) pj[n] = hpl[64 * 6 + n];
    for (int d8 = 0; d8 < 8; ++d8) {
        const short8 vh = *(const short8*)(qh + d8 * 8);
        const short8 vl = *(const short8*)(ql + d8 * 8);
#pragma unroll
        for (int e = 0; e < 8; ++e) {
            const float q = bff((unsigned short)vh[e]) + bff((unsigned short)vl[e]);
            nrm = fmaf(q, q, nrm);
#pragma unroll
            for (int n = 0; n < 6; ++n)
                pj[n] = fmaf(q, hpl[(d8 * 8 + e) * 6 + n], pj[n]);
        }
    }
    int bkt = 0;
#pragma unroll
    for (int n = 0; n < 6; ++n) bkt |= (pj[n] >= 0.f) << n;
    buckets[idx] = bkt;
    rown[idx] = nrm;
}

// ---------------------------------------------------------------------------
// Attention, split-K.  Grid (bh=32, qt=16, half=2); 4 waves x 32 q-rows.
// Each half sweeps K tokens [half*1024, half*1024+1024).  Per-block staging
// HALVES vs R8 -> total staged bytes unchanged at 2x blocks (4/CU, 16
// waves/CU).  Fixed upper-bound softmax -> partials merge exactly.
// Writes o-partials (no division) + l-partials.
// ---------------------------------------------------------------------------
__global__ __launch_bounds__(256, 2) void attn_kernel(
    const unsigned short* __restrict__ Qb, const unsigned short* __restrict__ Qlo,
    const unsigned short* __restrict__ Vt, const int* __restrict__ bks,
    const float* __restrict__ rown,
    float* __restrict__ op0, float* __restrict__ op1,
    float* __restrict__ lpart)
{
    __shared__ unsigned short Khi[64 * 64];
    __shared__ unsigned short Klo[64 * 64];
    __shared__ unsigned short Vs[64 * 64];
    __shared__ unsigned short P[4][16 * 64];
    __shared__ float smax[4];

    const int tid = threadIdx.x;
    const int w = tid >> 6, lane = tid & 63;
    const int i = lane & 15, qd = lane >> 4;
    const int l8 = lane >> 3, j = lane & 7;
    const int bh = blockIdx.x;
    const int qbase = blockIdx.y * 128 + w * 32;
    const int half = blockIdx.z;
    const int tbeg = half * 1024;

    const unsigned short* Qh = Qb + (size_t)bh * 2048 * 64;
    const unsigned short* Ql = Qlo + (size_t)bh * 2048 * 64;
    const unsigned short* Vb = Vt + (size_t)bh * 64 * 2048;
    const int* bk = bks + bh * 2048;
    const float* rnh = rown + bh * 2048;
    unsigned short* Pw = &P[w][0];
    float* op = half ? op1 : op0;

    float lm = 0.f;
    for (int t = tid; t < 2048; t += 256) lm = fmaxf(lm, rnh[t]);
#pragma unroll
    for (int msk = 1; msk < 64; msk <<= 1) lm = fmaxf(lm, __shfl_xor(lm, msk));
    if (lane == 0) smax[w] = lm;
    __syncthreads();
    const float sqM = sqrtf(fmaxf(fmaxf(smax[0], smax[1]),
                                  fmaxf(smax[2], smax[3])));

    float m2row[2][4], lrun[2][4];
    int qbr[2][4];
#pragma unroll
    for (int ms = 0; ms < 2; ++ms)
#pragma unroll
        for (int r = 0; r < 4; ++r) {
            const int row = qbase + ms * 16 + qd * 4 + r;
            m2row[ms][r] = 2.84030586f * sqrtf(rnh[row]) * sqM + 0.72134754f;
            qbr[ms][r] = bk[row];
            lrun[ms][r] = 0.f;
        }

    short8 aqh0[2], aqh1[2], aql0[2], aql1[2];
#pragma unroll
    for (int ms = 0; ms < 2; ++ms) {
        const unsigned short* qp = Qh + (size_t)(qbase + ms * 16 + i) * 64 + qd * 8;
        const unsigned short* lp = Ql + (size_t)(qbase + ms * 16 + i) * 64 + qd * 8;
        aqh0[ms] = *(const short8*)qp; aqh1[ms] = *(const short8*)(qp + 32);
        aql0[ms] = *(const short8*)lp; aql1[ms] = *(const short8*)(lp + 32);
    }

    f32x4 o[2][4];
#pragma unroll
    for (int ms = 0; ms < 2; ++ms)
#pragma unroll
        for (int d = 0; d < 4; ++d) o[ms][d] = f32x4{0.f, 0.f, 0.f, 0.f};

    for (int t0 = tbeg; t0 < tbeg + 1024; t0 += 64) {
        __syncthreads();
#pragma unroll
        for (int c2 = 0; c2 < 2; ++c2) {
            const int r = w * 16 + c2 * 8 + l8;
            const int swz = ((j ^ l8) << 3);
            glds16(Qh + (size_t)(t0 + r) * 64 + swz, &Khi[w * 1024 + c2 * 512]);
            glds16(Ql + (size_t)(t0 + r) * 64 + swz, &Klo[w * 1024 + c2 * 512]);
            glds16(Vb + (size_t)r * 2048 + t0 + swz, &Vs[w * 1024 + c2 * 512]);
        }
        __syncthreads();

        f32x4 s[2][4];
        int kb[4];
#pragma unroll
        for (int sub = 0; sub < 4; ++sub) {
            const int kr = sub * 16 + i;
            const int sw = i & 7;
            const short8 bh0 = *(const short8*)&Khi[kr * 64 + ((qd ^ sw) << 3)];
            const short8 bh1 = *(const short8*)&Khi[kr * 64 + (((qd + 4) ^ sw) << 3)];
            const short8 bl0 = *(const short8*)&Klo[kr * 64 + ((qd ^ sw) << 3)];
            const short8 bl1 = *(const short8*)&Klo[kr * 64 + (((qd + 4) ^ sw) << 3)];
            kb[sub] = bk[t0 + kr];
#pragma unroll
            for (int ms = 0; ms < 2; ++ms) {
                f32x4 t = f32x4{0.f, 0.f, 0.f, 0.f};
                t = __builtin_amdgcn_mfma_f32_16x16x32_bf16(aqh0[ms], bh0, t, 0, 0, 0);
                t = __builtin_amdgcn_mfma_f32_16x16x32_bf16(aqh1[ms], bh1, t, 0, 0, 0);
                t = __builtin_amdgcn_mfma_f32_16x16x32_bf16(aql0[ms], bh0, t, 0, 0, 0);
                t = __builtin_amdgcn_mfma_f32_16x16x32_bf16(aql1[ms], bh1, t, 0, 0, 0);
                t = __builtin_amdgcn_mfma_f32_16x16x32_bf16(aqh0[ms], bl0, t, 0, 0, 0);
                t = __builtin_amdgcn_mfma_f32_16x16x32_bf16(aqh1[ms], bl1, t, 0, 0, 0);
                s[ms][sub] = t;
            }
        }

        short8 vb0[4], vb1[4];
#pragma unroll
        for (int dsub = 0; dsub < 4; ++dsub) {
            const int dr = dsub * 16 + i;
            const int sw = i & 7;
            vb0[dsub] = *(const short8*)&Vs[dr * 64 + ((qd ^ sw) << 3)];
            vb1[dsub] = *(const short8*)&Vs[dr * 64 + (((qd + 4) ^ sw) << 3)];
        }

#pragma unroll
        for (int ms = 0; ms < 2; ++ms) {
#pragma unroll
            for (int sub = 0; sub < 4; ++sub)
#pragma unroll
                for (int r = 0; r < 4; ++r) {
                    const float c2f = (kb[sub] == qbr[ms][r]) ? 2.84030586f
                                                              : 2.79522164f;
                    const float p = exp2f(fmaf(s[ms][sub][r], c2f, -m2row[ms][r]));
                    lrun[ms][r] += p;
                    const unsigned int pu = __float_as_uint(p);
                    const int row = qd * 4 + r, col = sub * 16 + i;
                    Pw[row * 64 + (((col >> 3) ^ (row & 7)) << 3) + (col & 7)] =
                        (unsigned short)(pu >> 16);
                }
            const short8 pa0 = *(const short8*)&Pw[i * 64 + ((qd ^ (i & 7)) << 3)];
            const short8 pa1 = *(const short8*)&Pw[i * 64 + (((qd + 4) ^ (i & 7)) << 3)];
#pragma unroll
            for (int dsub = 0; dsub < 4; ++dsub) {
                o[ms][dsub] = __builtin_amdgcn_mfma_f32_16x16x32_bf16(
                    pa0, vb0[dsub], o[ms][dsub], 0, 0, 0);
                o[ms][dsub] = __builtin_amdgcn_mfma_f32_16x16x32_bf16(
                    pa1, vb1[dsub], o[ms][dsub], 0, 0, 0);
            }
        }
    }

#pragma unroll
    for (int ms = 0; ms < 2; ++ms)
#pragma unroll
        for (int r = 0; r < 4; ++r) {
#pragma unroll
            for (int msk = 1; msk < 16; msk <<= 1)
                lrun[ms][r] += __shfl_xor(lrun[ms][r], msk);
        }
    // partial outputs: o (undivided) and per-row l
#pragma unroll
    for (int ms = 0; ms < 2; ++ms) {
        if (i == 0) {
#pragma unroll
            for (int r = 0; r < 4; ++r) {
                const int srow = qbase + ms * 16 + qd * 4 + r;
                lpart[((size_t)(half * 32 + bh)) * 2048 + srow] = lrun[ms][r];
            }
        }
#pragma unroll
        for (int dsub = 0; dsub < 4; ++dsub)
#pragma unroll
            for (int r = 0; r < 4; ++r) {
                const int srow = qbase + ms * 16 + qd * 4 + r;
                op[((size_t)bh * 2048 + srow) * 64 + dsub * 16 + i] = o[ms][dsub][r];
            }
    }
}

// ---------------------------------------------------------------------------
// Merge: out = (o0+o1)/(l0+l1).  1,048,576 float4-units / 256 = 4096 blocks.
// ---------------------------------------------------------------------------
__global__ __launch_bounds__(256) void merge_kernel(
    const float* __restrict__ op0, const float* __restrict__ op1,
    const float* __restrict__ lpart, float* __restrict__ out)
{
    const int idx = blockIdx.x * 256 + threadIdx.x;   // 32 bh * 2048 row * 16 d4
    const int d4 = idx & 15;
    const int row = (idx >> 4) & 2047;
    const int bh = idx >> 15;
    const float l = lpart[(size_t)bh * 2048 + row] +
                    lpart[(size_t)(32 + bh) * 2048 + row];
    const float inv = 1.f / l;
    const float4 a = ((const float4*)op0)[((size_t)bh * 2048 + row) * 16 + d4];
    const float4 b4 = ((const float4*)op1)[((size_t)bh * 2048 + row) * 16 + d4];
    float4 v;
    v.x = (a.x + b4.x) * inv; v.y = (a.y + b4.y) * inv;
    v.z = (a.z + b4.z) * inv; v.w = (a.w + b4.w) * inv;
    const int b = bh >> 4, h = bh & 15;
    ((float4*)out)[((size_t)(b * 2048 + row)) * 256 + h * 16 + d4] = v;
}

// ---------------------------------------------------------------------------
extern "C" void kernel_launch(void* const* d_in, const int* in_sizes, int n_in,
                              void* d_out, int out_size, void* d_ws, size_t ws_size,
                              hipStream_t stream)
{
    const float* x  = (const float*)d_in[0];
    const float* Wq = (const float*)d_in[1];
    const float* bq = (const float*)d_in[2];
    const float* Wv = (const float*)d_in[3];
    const float* bv = (const float*)d_in[4];
    const float* hp = (const float*)d_in[5];
    float* out = (float*)d_out;

    char* ws = (char*)d_ws;
    const size_t MB = (size_t)1 << 20;
    unsigned short* xh  = (unsigned short*)(ws);            // 8 MB   [dead after gemm]
    unsigned short* xl  = (unsigned short*)(ws + 8 * MB);   // 8 MB   [dead after gemm]
    unsigned short* Wqh = (unsigned short*)(ws + 16 * MB);  // 2 MB   [dead after gemm]
    unsigned short* Wql = (unsigned short*)(ws + 18 * MB);  // 2 MB
    unsigned short* Wvh = (unsigned short*)(ws + 20 * MB);  // 2 MB
    unsigned short* Qb  = (unsigned short*)(ws + 22 * MB);  // 8 MB
    unsigned short* Qlo = (unsigned short*)(ws + 30 * MB);  // 8 MB
    unsigned short* Vt  = (unsigned short*)(ws + 38 * MB);  // 8 MB
    float*          op0 = (float*)(ws);                     // 16 MB over xh+xl (dead)
    float*          op1 = (float*)(ws + 46 * MB);           // 16 MB (old Qf region)
    float*        lpart = (float*)(ws + 16 * MB);           // 512 KB over Wqh (dead)
    int*        buckets = (int*)(ws + 62 * MB);             // 256 KB
    float*         rown = (float*)(ws + 62 * MB + 256 * 1024);  // 256 KB

    split_all<<<dim3(6144), 256, 0, stream>>>(x, Wq, Wv, xh, xl, Wqh, Wql, Wvh);
    gemm_qv<<<dim3(512), 256, 0, stream>>>(xh, xl, Wqh, Wql, Wvh, bq, bv,
                                           Qb, Qlo, Vt);
    bucket_kernel<<<dim3(256), 256, 0, stream>>>(Qb, Qlo, hp, buckets, rown);
    attn_kernel<<<dim3(32, 16, 2), 256, 0, stream>>>(Qb, Qlo, Vt, buckets, rown,
                                                     op0, op1, lpart);
    merge_kernel<<<dim3(4096), 256, 0, stream>>>(op0, op1, lpart, out);
}

// Round 10
// 213.185 us; speedup vs baseline: 1.0785x; 1.0785x over previous
//
#include <hip/hip_runtime.h>

// ---------------------------------------------------------------------------
// LSH attention, MI355X.  B=2, S=2048, E=1024, H=16, Dh=64, NB=64, NH=6.
// ALL inputs/outputs are FP32.
// R10: revert to R6-best (216.8us) + ONE change: gemm_qv block->tile remap
// for XCD L2 locality.  Default round-robin (XCD = blk%8) placed the 8
// blocks sharing an xh row-tile on 8 DIFFERENT XCDs -> xh+xl re-fetched
// into every L2 (~128MB Q + ~130MB V of L3->L2 traffic).  New mapping:
//   Q: m0 = (blk&7) + 8*((blk>>3)&3)  [m%8 == blk%8 == XCD], n0 = blk>>5
//   V: tok-tile = (b2&7) + 8*((b2>>3)&3), ch-tile = b2>>5
// so all blocks sharing an x-tile land on one XCD (Q and V agree on the
// tile->XCD map).  Pure index permutation: bit-identical outputs.
// Split-K attn (R8/R9) abandoned: occupancy never moved (21%) and merge
// overhead cost +13us -- occupancy is a dead end on this structure.
//   0) split_all: x -> xh+xl, Wq -> Wqh+Wql, Wv -> Wvh in ONE launch
//   1) gemm_qv: 512 blocks, 128x128, BK=64, bounds(256,2), XCD-remapped
//   2) bucket_kernel: bucket bits from hi+lo q; row |q|^2
//   3) attn_kernel: EXACT verified R8 (grid (32,16), 4 waves x 32 q-rows)
// ---------------------------------------------------------------------------

typedef short short8 __attribute__((ext_vector_type(8)));
typedef float f32x4 __attribute__((ext_vector_type(4)));
typedef unsigned short us4 __attribute__((ext_vector_type(4)));

__device__ __forceinline__ float bff(unsigned short h) {
    return __uint_as_float(((unsigned int)h) << 16);
}
__device__ __forceinline__ unsigned short f2bf(float f) {  // RNE, finite inputs
    unsigned int u = __float_as_uint(f);
    u += 0x7fffu + ((u >> 16) & 1u);
    return (unsigned short)(u >> 16);
}

__device__ __forceinline__ void glds16(const unsigned short* g, unsigned short* l) {
    __builtin_amdgcn_global_load_lds(
        (const __attribute__((address_space(1))) unsigned int*)g,
        (__attribute__((address_space(3))) unsigned int*)l, 16, 0, 0);
}

// ---------------------------------------------------------------------------
// Fused split: blk<4096 -> x (hi+lo); <5120 -> Wq (hi+lo); else Wv (hi).
// ---------------------------------------------------------------------------
__global__ __launch_bounds__(256) void split_all(
    const float* __restrict__ x, const float* __restrict__ Wq,
    const float* __restrict__ Wv,
    unsigned short* __restrict__ xh, unsigned short* __restrict__ xl,
    unsigned short* __restrict__ Wqh, unsigned short* __restrict__ Wql,
    unsigned short* __restrict__ Wvh)
{
    const int blk = blockIdx.x;
    const float* in;
    unsigned short *hi, *lo;
    int idx;
    if (blk < 4096) {
        idx = blk * 256 + threadIdx.x; in = x; hi = xh; lo = xl;
    } else if (blk < 5120) {
        idx = (blk - 4096) * 256 + threadIdx.x; in = Wq; hi = Wqh; lo = Wql;
    } else {
        idx = (blk - 5120) * 256 + threadIdx.x; in = Wv; hi = Wvh; lo = nullptr;
    }
    const float4 v = ((const float4*)in)[idx];
    us4 h;
    h.x = f2bf(v.x); h.y = f2bf(v.y); h.z = f2bf(v.z); h.w = f2bf(v.w);
    ((us4*)hi)[idx] = h;
    if (lo) {
        us4 l;
        l.x = f2bf(v.x - bff(h.x)); l.y = f2bf(v.y - bff(h.y));
        l.z = f2bf(v.z - bff(h.z)); l.w = f2bf(v.w - bff(h.w));
        ((us4*)lo)[idx] = l;
    }
}

// ---------------------------------------------------------------------------
// Merged projection GEMM.  512 blocks: b<256 Q path (3-term hi/lo); b>=256
// V path.  128x128 tile, BK=64, LDS staged with global-side XOR swizzle.
// R10: tile indices remapped so blocks sharing an x row-tile share an XCD
// (XCD = blk%8 under round-robin dispatch).  bounds(256,2) -> 2 blocks/CU.
// ---------------------------------------------------------------------------
__global__ __launch_bounds__(256, 2) void gemm_qv(
    const unsigned short* __restrict__ xh, const unsigned short* __restrict__ xl,
    const unsigned short* __restrict__ wqh, const unsigned short* __restrict__ wql,
    const unsigned short* __restrict__ wvh,
    const float* __restrict__ bq, const float* __restrict__ bv,
    unsigned short* __restrict__ Qb, unsigned short* __restrict__ Qlo,
    unsigned short* __restrict__ Vt)
{
    __shared__ unsigned short Ah[128 * 64], Al[128 * 64];
    __shared__ unsigned short Bh[128 * 64], Bl[128 * 64];

    const int tid = threadIdx.x;
    const int w = tid >> 6, lane = tid & 63;
    const int i = lane & 15, qd = lane >> 4;
    const int l8 = lane >> 3, j = lane & 7;
    const int nw = w * 32;
    const int blk = blockIdx.x;
    const bool isq = blk < 256;

    f32x4 acc[8][2];
#pragma unroll
    for (int a = 0; a < 8; ++a)
#pragma unroll
        for (int b2 = 0; b2 < 2; ++b2) acc[a][b2] = f32x4{0.f, 0.f, 0.f, 0.f};

    const int gro = ((j ^ l8) << 3);

    if (isq) {
        // XCD-locality remap: m-tile%8 == blk%8 (== XCD under round-robin)
        const int m0 = ((blk & 7) + 8 * ((blk >> 3) & 3)) * 128;  // token tile
        const int n0 = (blk >> 5) * 128;                          // channel tile
        for (int k0 = 0; k0 < 1024; k0 += 64) {
            __syncthreads();
#pragma unroll
            for (int c = 0; c < 4; ++c) {
                const int r = w * 32 + c * 8;
                const size_t gx = (size_t)(m0 + r + l8) * 1024 + k0 + gro;
                const size_t gw = (size_t)(n0 + r + l8) * 1024 + k0 + gro;
                glds16(xh + gx, &Ah[r * 64]);
                glds16(xl + gx, &Al[r * 64]);
                glds16(wqh + gw, &Bh[r * 64]);
                glds16(wql + gw, &Bl[r * 64]);
            }
            __syncthreads();
#pragma unroll
            for (int kc = 0; kc < 2; ++kc) {
                const int ch = (((kc * 4 + qd) ^ (i & 7)) << 3);
                short8 bh2[2], bl2[2];
#pragma unroll
                for (int nn = 0; nn < 2; ++nn) {
                    bh2[nn] = *(const short8*)&Bh[(nw + nn * 16 + i) * 64 + ch];
                    bl2[nn] = *(const short8*)&Bl[(nw + nn * 16 + i) * 64 + ch];
                }
#pragma unroll
                for (int mm = 0; mm < 8; ++mm) {
                    const short8 ah = *(const short8*)&Ah[(mm * 16 + i) * 64 + ch];
                    const short8 al = *(const short8*)&Al[(mm * 16 + i) * 64 + ch];
#pragma unroll
                    for (int nn = 0; nn < 2; ++nn) {
                        acc[mm][nn] = __builtin_amdgcn_mfma_f32_16x16x32_bf16(
                            ah, bh2[nn], acc[mm][nn], 0, 0, 0);
                        acc[mm][nn] = __builtin_amdgcn_mfma_f32_16x16x32_bf16(
                            al, bh2[nn], acc[mm][nn], 0, 0, 0);
                        acc[mm][nn] = __builtin_amdgcn_mfma_f32_16x16x32_bf16(
                            ah, bl2[nn], acc[mm][nn], 0, 0, 0);
                    }
                }
            }
        }
#pragma unroll
        for (int mm = 0; mm < 8; ++mm)
#pragma unroll
            for (int nn = 0; nn < 2; ++nn)
#pragma unroll
                for (int rr = 0; rr < 4; ++rr) {
                    const int row = m0 + mm * 16 + qd * 4 + rr;  // token
                    const int col = n0 + nw + nn * 16 + i;       // channel
                    const float v = acc[mm][nn][rr] + bq[col];
                    const unsigned short hs = f2bf(v);
                    const float lo = v - bff(hs);
                    const int b = row >> 11, s = row & 2047;
                    const int hh = col >> 6, d = col & 63;
                    const size_t oi = ((size_t)((b << 4) + hh) * 2048 + s) * 64 + d;
                    Qb[oi] = hs;
                    Qlo[oi] = f2bf(lo);
                }
    } else {
        const int b2 = blk - 256;
        // XCD-locality remap: token-tile%8 == b2%8 (same map as Q's x-tiles)
        const int n0 = ((b2 & 7) + 8 * ((b2 >> 3) & 3)) * 128;  // token tile
        const int m0 = (b2 >> 5) * 128;                         // channel tile
        for (int k0 = 0; k0 < 1024; k0 += 64) {
            __syncthreads();
#pragma unroll
            for (int c = 0; c < 4; ++c) {
                const int r = w * 32 + c * 8;
                glds16(wvh + (size_t)(m0 + r + l8) * 1024 + k0 + gro, &Ah[r * 64]);
                glds16(xh + (size_t)(n0 + r + l8) * 1024 + k0 + gro, &Bh[r * 64]);
            }
            __syncthreads();
#pragma unroll
            for (int kc = 0; kc < 2; ++kc) {
                const int ch = (((kc * 4 + qd) ^ (i & 7)) << 3);
                short8 bf2[2];
#pragma unroll
                for (int nn = 0; nn < 2; ++nn)
                    bf2[nn] = *(const short8*)&Bh[(nw + nn * 16 + i) * 64 + ch];
#pragma unroll
                for (int mm = 0; mm < 8; ++mm) {
                    const short8 af = *(const short8*)&Ah[(mm * 16 + i) * 64 + ch];
#pragma unroll
                    for (int nn = 0; nn < 2; ++nn)
                        acc[mm][nn] = __builtin_amdgcn_mfma_f32_16x16x32_bf16(
                            af, bf2[nn], acc[mm][nn], 0, 0, 0);
                }
            }
        }
#pragma unroll
        for (int mm = 0; mm < 8; ++mm)
#pragma unroll
            for (int nn = 0; nn < 2; ++nn)
#pragma unroll
                for (int rr = 0; rr < 4; ++rr) {
                    const int rch = m0 + mm * 16 + qd * 4 + rr;  // channel
                    const int tok = n0 + nw + nn * 16 + i;       // token
                    const float v = acc[mm][nn][rr] + bv[rch];
                    const int b = tok >> 11, s = tok & 2047;
                    Vt[((size_t)(b * 1024 + rch)) * 2048 + s] = f2bf(v);
                }
    }
}

// ---------------------------------------------------------------------------
// Buckets + row norms.  q reconstructed as hi+lo from Qb/Qlo.
// ---------------------------------------------------------------------------
__global__ __launch_bounds__(256) void bucket_kernel(
    const unsigned short* __restrict__ Qb, const unsigned short* __restrict__ Qlo,
    const float* __restrict__ hp,
    int* __restrict__ buckets, float* __restrict__ rown)
{
    __shared__ float hpl[65 * 6];
    const int tid = threadIdx.x;
    if (tid < 65 * 6) hpl[tid] = hp[tid];
    __syncthreads();

    const int idx = blockIdx.x * 256 + tid;       // 65536 = 32 bh * 2048 s
    const unsigned short* qh = Qb + (size_t)idx * 64;
    const unsigned short* ql = Qlo + (size_t)idx * 64;

    float pj[6];
    float nrm = 0.f;
#pragma unroll
    for (int n = 0; n < 6; ++n) pj[n] = hpl[64 * 6 + n];
    for (int d8 = 0; d8 < 8; ++d8) {
        const short8 vh = *(const short8*)(qh + d8 * 8);
        const short8 vl = *(const short8*)(ql + d8 * 8);
#pragma unroll
        for (int e = 0; e < 8; ++e) {
            const float q = bff((unsigned short)vh[e]) + bff((unsigned short)vl[e]);
            nrm = fmaf(q, q, nrm);
#pragma unroll
            for (int n = 0; n < 6; ++n)
                pj[n] = fmaf(q, hpl[(d8 * 8 + e) * 6 + n], pj[n]);
        }
    }
    int bkt = 0;
#pragma unroll
    for (int n = 0; n < 6; ++n) bkt |= (pj[n] >= 0.f) << n;
    buckets[idx] = bkt;
    rown[idx] = nrm;
}

// ---------------------------------------------------------------------------
// Attention (EXACT verified R8 v6).  Grid (bh=32, qt=16); 4 waves; wave owns
// 32 q-rows (2 ms); K-tile 64 LDS-staged with global-side XOR swizzle.
// Fixed upper-bound softmax shift; P high-half pack.  LDS 33 KB.
// ---------------------------------------------------------------------------
__global__ __launch_bounds__(256, 2) void attn_kernel(
    const unsigned short* __restrict__ Qb, const unsigned short* __restrict__ Qlo,
    const unsigned short* __restrict__ Vt, const int* __restrict__ bks,
    const float* __restrict__ rown, float* __restrict__ out)
{
    __shared__ unsigned short Khi[64 * 64];
    __shared__ unsigned short Klo[64 * 64];
    __shared__ unsigned short Vs[64 * 64];
    __shared__ unsigned short P[4][16 * 64];
    __shared__ float smax[4];

    const int tid = threadIdx.x;
    const int w = tid >> 6, lane = tid & 63;
    const int i = lane & 15, qd = lane >> 4;
    const int l8 = lane >> 3, j = lane & 7;
    const int bh = blockIdx.x;
    const int qbase = blockIdx.y * 128 + w * 32;

    const unsigned short* Qh = Qb + (size_t)bh * 2048 * 64;
    const unsigned short* Ql = Qlo + (size_t)bh * 2048 * 64;
    const unsigned short* Vb = Vt + (size_t)bh * 64 * 2048;
    const int* bk = bks + bh * 2048;
    const float* rnh = rown + bh * 2048;
    unsigned short* Pw = &P[w][0];

    float lm = 0.f;
    for (int t = tid; t < 2048; t += 256) lm = fmaxf(lm, rnh[t]);
#pragma unroll
    for (int msk = 1; msk < 64; msk <<= 1) lm = fmaxf(lm, __shfl_xor(lm, msk));
    if (lane == 0) smax[w] = lm;
    __syncthreads();
    const float sqM = sqrtf(fmaxf(fmaxf(smax[0], smax[1]),
                                  fmaxf(smax[2], smax[3])));

    float m2row[2][4], lrun[2][4];
    int qbr[2][4];
#pragma unroll
    for (int ms = 0; ms < 2; ++ms)
#pragma unroll
        for (int r = 0; r < 4; ++r) {
            const int row = qbase + ms * 16 + qd * 4 + r;
            m2row[ms][r] = 2.84030586f * sqrtf(rnh[row]) * sqM + 0.72134754f;
            qbr[ms][r] = bk[row];
            lrun[ms][r] = 0.f;
        }

    short8 aqh0[2], aqh1[2], aql0[2], aql1[2];
#pragma unroll
    for (int ms = 0; ms < 2; ++ms) {
        const unsigned short* qp = Qh + (size_t)(qbase + ms * 16 + i) * 64 + qd * 8;
        const unsigned short* lp = Ql + (size_t)(qbase + ms * 16 + i) * 64 + qd * 8;
        aqh0[ms] = *(const short8*)qp; aqh1[ms] = *(const short8*)(qp + 32);
        aql0[ms] = *(const short8*)lp; aql1[ms] = *(const short8*)(lp + 32);
    }

    f32x4 o[2][4];
#pragma unroll
    for (int ms = 0; ms < 2; ++ms)
#pragma unroll
        for (int d = 0; d < 4; ++d) o[ms][d] = f32x4{0.f, 0.f, 0.f, 0.f};

    for (int t0 = 0; t0 < 2048; t0 += 64) {
        __syncthreads();
#pragma unroll
        for (int c2 = 0; c2 < 2; ++c2) {
            const int r = w * 16 + c2 * 8 + l8;
            const int swz = ((j ^ l8) << 3);
            glds16(Qh + (size_t)(t0 + r) * 64 + swz, &Khi[w * 1024 + c2 * 512]);
            glds16(Ql + (size_t)(t0 + r) * 64 + swz, &Klo[w * 1024 + c2 * 512]);
            glds16(Vb + (size_t)r * 2048 + t0 + swz, &Vs[w * 1024 + c2 * 512]);
        }
        __syncthreads();

        f32x4 s[2][4];
        int kb[4];
#pragma unroll
        for (int sub = 0; sub < 4; ++sub) {
            const int kr = sub * 16 + i;
            const int sw = i & 7;
            const short8 bh0 = *(const short8*)&Khi[kr * 64 + ((qd ^ sw) << 3)];
            const short8 bh1 = *(const short8*)&Khi[kr * 64 + (((qd + 4) ^ sw) << 3)];
            const short8 bl0 = *(const short8*)&Klo[kr * 64 + ((qd ^ sw) << 3)];
            const short8 bl1 = *(const short8*)&Klo[kr * 64 + (((qd + 4) ^ sw) << 3)];
            kb[sub] = bk[t0 + kr];
#pragma unroll
            for (int ms = 0; ms < 2; ++ms) {
                f32x4 t = f32x4{0.f, 0.f, 0.f, 0.f};
                t = __builtin_amdgcn_mfma_f32_16x16x32_bf16(aqh0[ms], bh0, t, 0, 0, 0);
                t = __builtin_amdgcn_mfma_f32_16x16x32_bf16(aqh1[ms], bh1, t, 0, 0, 0);
                t = __builtin_amdgcn_mfma_f32_16x16x32_bf16(aql0[ms], bh0, t, 0, 0, 0);
                t = __builtin_amdgcn_mfma_f32_16x16x32_bf16(aql1[ms], bh1, t, 0, 0, 0);
                t = __builtin_amdgcn_mfma_f32_16x16x32_bf16(aqh0[ms], bl0, t, 0, 0, 0);
                t = __builtin_amdgcn_mfma_f32_16x16x32_bf16(aqh1[ms], bl1, t, 0, 0, 0);
                s[ms][sub] = t;
            }
        }

        short8 vb0[4], vb1[4];
#pragma unroll
        for (int dsub = 0; dsub < 4; ++dsub) {
            const int dr = dsub * 16 + i;
            const int sw = i & 7;
            vb0[dsub] = *(const short8*)&Vs[dr * 64 + ((qd ^ sw) << 3)];
            vb1[dsub] = *(const short8*)&Vs[dr * 64 + (((qd + 4) ^ sw) << 3)];
        }

#pragma unroll
        for (int ms = 0; ms < 2; ++ms) {
#pragma unroll
            for (int sub = 0; sub < 4; ++sub)
#pragma unroll
                for (int r = 0; r < 4; ++r) {
                    const float c2f = (kb[sub] == qbr[ms][r]) ? 2.84030586f
                                                              : 2.79522164f;
                    const float p = exp2f(fmaf(s[ms][sub][r], c2f, -m2row[ms][r]));
                    lrun[ms][r] += p;
                    const unsigned int pu = __float_as_uint(p);
                    const int row = qd * 4 + r, col = sub * 16 + i;
                    Pw[row * 64 + (((col >> 3) ^ (row & 7)) << 3) + (col & 7)] =
                        (unsigned short)(pu >> 16);
                }
            const short8 pa0 = *(const short8*)&Pw[i * 64 + ((qd ^ (i & 7)) << 3)];
            const short8 pa1 = *(const short8*)&Pw[i * 64 + (((qd + 4) ^ (i & 7)) << 3)];
#pragma unroll
            for (int dsub = 0; dsub < 4; ++dsub) {
                o[ms][dsub] = __builtin_amdgcn_mfma_f32_16x16x32_bf16(
                    pa0, vb0[dsub], o[ms][dsub], 0, 0, 0);
                o[ms][dsub] = __builtin_amdgcn_mfma_f32_16x16x32_bf16(
                    pa1, vb1[dsub], o[ms][dsub], 0, 0, 0);
            }
        }
    }

#pragma unroll
    for (int ms = 0; ms < 2; ++ms)
#pragma unroll
        for (int r = 0; r < 4; ++r) {
#pragma unroll
            for (int msk = 1; msk < 16; msk <<= 1)
                lrun[ms][r] += __shfl_xor(lrun[ms][r], msk);
        }
    const int b = bh >> 4, h = bh & 15;
#pragma unroll
    for (int ms = 0; ms < 2; ++ms)
#pragma unroll
        for (int dsub = 0; dsub < 4; ++dsub)
#pragma unroll
            for (int r = 0; r < 4; ++r) {
                const float v = o[ms][dsub][r] / lrun[ms][r];
                const int srow = qbase + ms * 16 + qd * 4 + r;
                out[((size_t)(b * 2048 + srow)) * 1024 + h * 64 + dsub * 16 + i] = v;
            }
}

// ---------------------------------------------------------------------------
extern "C" void kernel_launch(void* const* d_in, const int* in_sizes, int n_in,
                              void* d_out, int out_size, void* d_ws, size_t ws_size,
                              hipStream_t stream)
{
    const float* x  = (const float*)d_in[0];
    const float* Wq = (const float*)d_in[1];
    const float* bq = (const float*)d_in[2];
    const float* Wv = (const float*)d_in[3];
    const float* bv = (const float*)d_in[4];
    const float* hp = (const float*)d_in[5];
    float* out = (float*)d_out;

    char* ws = (char*)d_ws;
    const size_t MB = (size_t)1 << 20;
    unsigned short* xh  = (unsigned short*)(ws);            // 8 MB
    unsigned short* xl  = (unsigned short*)(ws + 8 * MB);   // 8 MB
    unsigned short* Wqh = (unsigned short*)(ws + 16 * MB);  // 2 MB
    unsigned short* Wql = (unsigned short*)(ws + 18 * MB);  // 2 MB
    unsigned short* Wvh = (unsigned short*)(ws + 20 * MB);  // 2 MB
    unsigned short* Qb  = (unsigned short*)(ws + 22 * MB);  // 8 MB
    unsigned short* Qlo = (unsigned short*)(ws + 30 * MB);  // 8 MB
    unsigned short* Vt  = (unsigned short*)(ws + 38 * MB);  // 8 MB
    int*        buckets = (int*)(ws + 62 * MB);             // 256 KB
    float*         rown = (float*)(ws + 62 * MB + 256 * 1024);  // 256 KB

    split_all<<<dim3(6144), 256, 0, stream>>>(x, Wq, Wv, xh, xl, Wqh, Wql, Wvh);
    gemm_qv<<<dim3(512), 256, 0, stream>>>(xh, xl, Wqh, Wql, Wvh, bq, bv,
                                           Qb, Qlo, Vt);
    bucket_kernel<<<dim3(256), 256, 0, stream>>>(Qb, Qlo, hp, buckets, rown);
    attn_kernel<<<dim3(32, 16), 256, 0, stream>>>(Qb, Qlo, Vt, buckets, rown, out);
}